// Round 2
// baseline (1330.737 us; speedup 1.0000x reference)
//
#include <hip/hip_runtime.h>
#include <hip/hip_bf16.h>

typedef __hip_bfloat16 bf16;

// LiteMLA pipeline, bf16 intermediates / fp32 accumulation.
// Dims (fixed by the problem):
#define BATCH 4
#define CIN   512
#define HW    64
#define NPIX  4096          // 64*64
#define CALL  3072          // qkv(1536) + pw(1536)
#define NHEAD 128
#define EPS_LITE 1e-15f
#define BN_EPS   1e-5f

// Workspace layout (bytes) — total ~129.3 MiB (fits conservative ws_size):
//   qkv_all (bf16): 0         .. 100663296   (4*3072*4096*2)
//   att     (bf16): 100663296 .. 134217728   (4*1024*4096*2)
//   part    (f32) : 134217728 .. 135397376   (4*128*72*8*4)
//   scores  (f32) : 135397376 .. 135544832   (4*128*72*4)

// ---------------------------------------------------------------------------
// K1: QKV projection GEMM. out[b,c,n] = sum_k x[b,k,n] * w[c,k]
// grid (16 ntiles, 96 cgroups, 4), block 256. 16 channels per thread.
__global__ __launch_bounds__(256) void k_qkv(const float* __restrict__ x,
                                             const float* __restrict__ wq,
                                             const float* __restrict__ wk,
                                             const float* __restrict__ wv,
                                             bf16* __restrict__ qkv_all) {
    const int n  = blockIdx.x * 256 + threadIdx.x;
    const int c0 = blockIdx.y * 16;
    const int b  = blockIdx.z;

    const float* w;
    int cr;
    if (c0 < 512)       { w = wq; cr = c0; }
    else if (c0 < 1024) { w = wk; cr = c0 - 512; }
    else                { w = wv; cr = c0 - 1024; }

    const float* xp = x + (size_t)b * CIN * NPIX + n;

    float acc[16];
#pragma unroll
    for (int j = 0; j < 16; ++j) acc[j] = 0.f;

#pragma unroll 4
    for (int k = 0; k < 512; ++k) {
        const float xv = xp[(size_t)k * NPIX];
#pragma unroll
        for (int j = 0; j < 16; ++j)
            acc[j] += w[(cr + j) * 512 + k] * xv;   // wave-uniform -> s_load
    }

    bf16* op = qkv_all + ((size_t)b * CALL + c0) * NPIX + n;
#pragma unroll
    for (int j = 0; j < 16; ++j) op[(size_t)j * NPIX] = __float2bfloat16(acc[j]);
}

// ---------------------------------------------------------------------------
// K2: fused depthwise 5x5 (SAME, zero pad) + grouped 1x1 (8in->8out per group).
// Reads qkv_all channels [0,1536), writes channels [1536,3072). Disjoint.
// grid (16 ntiles, 192 groups, 4), block 256.
__global__ __launch_bounds__(256) void k_dwpw(const float* __restrict__ dwk,
                                              const float* __restrict__ pwk,
                                              bf16* __restrict__ qkv_all) {
    const int n = blockIdx.x * 256 + threadIdx.x;
    const int g = blockIdx.y;
    const int b = blockIdx.z;
    const int y  = n >> 6;
    const int xx = n & 63;

    float dwv[8];
#pragma unroll
    for (int ci = 0; ci < 8; ++ci) {
        const int c = g * 8 + ci;
        const bf16* ip = qkv_all + ((size_t)b * CALL + c) * NPIX;
        const float* kp = dwk + c * 25;             // wave-uniform
        float s = 0.f;
#pragma unroll
        for (int i = 0; i < 5; ++i) {
            const int yy = y + i - 2;
            if (yy < 0 || yy >= HW) continue;
#pragma unroll
            for (int j = 0; j < 5; ++j) {
                const int xj = xx + j - 2;
                const float v = (xj >= 0 && xj < HW) ? __bfloat162float(ip[yy * HW + xj]) : 0.f;
                s += kp[i * 5 + j] * v;
            }
        }
        dwv[ci] = s;
    }

#pragma unroll
    for (int o = 0; o < 8; ++o) {
        const int co = g * 8 + o;
        float s = 0.f;
#pragma unroll
        for (int ci = 0; ci < 8; ++ci) s += pwk[co * 8 + ci] * dwv[ci];
        qkv_all[((size_t)b * CALL + 1536 + co) * NPIX + n] = __float2bfloat16(s);
    }
}

// ---------------------------------------------------------------------------
// K3: scores[b,h,d,e] = sum_n vpad[d,n]*relu(key[e,n]); partial per n-slice.
// grid (8 nslices, 128 heads, 4), block 64 (one wave).
__global__ __launch_bounds__(64) void k_scores(const bf16* __restrict__ qkv_all,
                                               float* __restrict__ part) {
    const int lane = threadIdx.x;
    const int h = blockIdx.y;
    const int b = blockIdx.z;
    const bf16* base = qkv_all + ((size_t)b * CALL + h * 24) * NPIX;

    float acc[72];
#pragma unroll
    for (int i = 0; i < 72; ++i) acc[i] = 0.f;

    for (int it = 0; it < 8; ++it) {
        const int n = blockIdx.x * 512 + it * 64 + lane;
        const bf16* p = base + n;
        float kv[8], vv[8];
#pragma unroll
        for (int e = 0; e < 8; ++e) kv[e] = fmaxf(__bfloat162float(p[(size_t)(8 + e) * NPIX]), 0.f);
#pragma unroll
        for (int d = 0; d < 8; ++d) vv[d] = __bfloat162float(p[(size_t)(16 + d) * NPIX]);
#pragma unroll
        for (int d = 0; d < 9; ++d) {
            const float vd = (d < 8) ? vv[d] : 1.f;
#pragma unroll
            for (int e = 0; e < 8; ++e) acc[d * 8 + e] += vd * kv[e];
        }
    }

    const int bh = b * NHEAD + h;
#pragma unroll
    for (int i = 0; i < 72; ++i) {
        float v = acc[i];
        for (int off = 32; off; off >>= 1) v += __shfl_xor(v, off, 64);
        if (lane == 0) part[((size_t)bh * 72 + i) * 8 + blockIdx.x] = v;
    }
}

// K3b: sum the 8 n-slice partials. grid 512 (b*h), block 128 (72 active).
__global__ __launch_bounds__(128) void k_scores2(const float* __restrict__ part,
                                                 float* __restrict__ scores) {
    const int bh = blockIdx.x;
    const int i = threadIdx.x;
    if (i < 72) {
        float s = 0.f;
#pragma unroll
        for (int ns = 0; ns < 8; ++ns) s += part[((size_t)bh * 72 + i) * 8 + ns];
        scores[(size_t)bh * 72 + i] = s;
    }
}

// ---------------------------------------------------------------------------
// K4a: att[b, h*8+d, n] = (sum_e scores[d,e]*relu(q[e,n])) / (den + EPS)
// grid (16 ntiles, 128 heads, 4), block 256.
__global__ __launch_bounds__(256) void k_att(const bf16* __restrict__ qkv_all,
                                             const float* __restrict__ scores,
                                             bf16* __restrict__ att) {
    const int n = blockIdx.x * 256 + threadIdx.x;
    const int h = blockIdx.y;
    const int b = blockIdx.z;

    const bf16* qb = qkv_all + ((size_t)b * CALL + h * 24) * NPIX + n;
    float q[8];
#pragma unroll
    for (int e = 0; e < 8; ++e) q[e] = fmaxf(__bfloat162float(qb[(size_t)e * NPIX]), 0.f);

    const float* sp = scores + (size_t)(b * NHEAD + h) * 72;  // wave-uniform
    float num[9];
#pragma unroll
    for (int d = 0; d < 9; ++d) {
        float s = 0.f;
#pragma unroll
        for (int e = 0; e < 8; ++e) s += sp[d * 8 + e] * q[e];
        num[d] = s;
    }
    const float invden = 1.f / (num[8] + EPS_LITE);
    bf16* op = att + ((size_t)b * 1024 + h * 8) * NPIX + n;
#pragma unroll
    for (int d = 0; d < 8; ++d) op[(size_t)d * NPIX] = __float2bfloat16(num[d] * invden);
}

// ---------------------------------------------------------------------------
// K4b: proj GEMM (K=1024) + batchnorm + residual.
// grid (16 ntiles, 32 ogroups, 4), block 256. 16 out-channels per thread.
__global__ __launch_bounds__(256) void k_proj(const bf16* __restrict__ att,
                                              const float* __restrict__ proj,
                                              const float* __restrict__ gamma,
                                              const float* __restrict__ beta,
                                              const float* __restrict__ mean,
                                              const float* __restrict__ var,
                                              const float* __restrict__ x,
                                              float* __restrict__ out) {
    const int n  = blockIdx.x * 256 + threadIdx.x;
    const int o0 = blockIdx.y * 16;
    const int b  = blockIdx.z;

    const bf16* ap = att + (size_t)b * 1024 * NPIX + n;

    float acc[16];
#pragma unroll
    for (int j = 0; j < 16; ++j) acc[j] = 0.f;

#pragma unroll 4
    for (int c = 0; c < 1024; ++c) {
        const float av = __bfloat162float(ap[(size_t)c * NPIX]);
#pragma unroll
        for (int j = 0; j < 16; ++j)
            acc[j] += proj[(o0 + j) * 1024 + c] * av;   // wave-uniform -> s_load
    }

#pragma unroll
    for (int j = 0; j < 16; ++j) {
        const int o = o0 + j;
        const float inv = gamma[o] / sqrtf(var[o] + BN_EPS);
        const float sh  = beta[o] - mean[o] * inv;
        const size_t idx = ((size_t)b * 512 + o) * NPIX + n;
        out[idx] = acc[j] * inv + sh + x[idx];
    }
}

// ---------------------------------------------------------------------------
extern "C" void kernel_launch(void* const* d_in, const int* in_sizes, int n_in,
                              void* d_out, int out_size, void* d_ws, size_t ws_size,
                              hipStream_t stream) {
    const float* x   = (const float*)d_in[0];
    const float* wq  = (const float*)d_in[1];
    const float* wk  = (const float*)d_in[2];
    const float* wv  = (const float*)d_in[3];
    const float* dwk = (const float*)d_in[4];
    const float* pwk = (const float*)d_in[5];
    const float* pj  = (const float*)d_in[6];
    const float* gm  = (const float*)d_in[7];
    const float* bt  = (const float*)d_in[8];
    const float* mu  = (const float*)d_in[9];
    const float* va  = (const float*)d_in[10];
    float* out = (float*)d_out;

    char* ws = (char*)d_ws;
    bf16*  qkv_all = (bf16*)(ws);
    bf16*  att     = (bf16*)(ws + 100663296);
    float* part    = (float*)(ws + 134217728);
    float* scores  = (float*)(ws + 135397376);

    k_qkv    <<<dim3(16,  96, BATCH), 256, 0, stream>>>(x, wq, wk, wv, qkv_all);
    k_dwpw   <<<dim3(16, 192, BATCH), 256, 0, stream>>>(dwk, pwk, qkv_all);
    k_scores <<<dim3( 8, 128, BATCH),  64, 0, stream>>>(qkv_all, part);
    k_scores2<<<dim3(512), 128, 0, stream>>>(part, scores);
    k_att    <<<dim3(16, 128, BATCH), 256, 0, stream>>>(qkv_all, scores, att);
    k_proj   <<<dim3(16,  32, BATCH), 256, 0, stream>>>(att, pj, gm, bt, mu, va, x, out);
}

// Round 3
// 394.467 us; speedup vs baseline: 3.3735x; 3.3735x over previous
//
#include <hip/hip_runtime.h>
#include <hip/hip_bf16.h>

typedef __hip_bfloat16 bf16;
typedef __attribute__((ext_vector_type(8))) short bf16x8;
typedef __attribute__((ext_vector_type(4))) float f32x4;
typedef __attribute__((ext_vector_type(2))) float f32x2;

#define BATCH 4
#define CIN   512
#define HW    64
#define NPIX  4096
#define CALL  3072
#define NHEAD 128
#define EPS_LITE 1e-15f
#define BN_EPS   1e-5f
#define LDK   40            // padded LDS K-stride (elems): 80B rows -> 2-way banks (free)

// Workspace (bytes), total ~129.3 MiB:
//   qkv_all (bf16): 0         .. 100663296
//   att     (bf16): 100663296 .. 134217728
//   part    (f32) : 134217728 .. 135397376
//   scores  (f32) : 135397376 .. 135544832

__device__ __forceinline__ short f2bf(float f) {
    __hip_bfloat16 h = __float2bfloat16(f);
    short s; __builtin_memcpy(&s, &h, 2); return s;
}

// ---------------------------------------------------------------------------
// MFMA GEMM: C[c][n] = sum_k W[c][k] * X[k][n], per batch b.
// Tile 64c x 128n x 32k, 4 waves (2x2), double-buffered LDS, 1 barrier/step.
// XF32: X is fp32 (qkv path, X=hidden_states). Else X is bf16 (proj path, X=att).
// PROJ: epilogue = BN + residual, fp32 out. Else: bf16 store into qkv_all.
template<bool XF32, int KD, bool PROJ>
__global__ __launch_bounds__(256) void k_gemm(
        const void* __restrict__ Xv,
        const float* __restrict__ w0, const float* __restrict__ w1,
        const float* __restrict__ w2,
        bf16* __restrict__ Obf,
        const float* __restrict__ gm, const float* __restrict__ bt,
        const float* __restrict__ mu, const float* __restrict__ va,
        const float* __restrict__ resid, float* __restrict__ Of)
{
    constexpr int NT = KD / 32;
    __shared__ short Ald[2][64 * LDK];
    __shared__ short Bld[2][128 * LDK];

    const int t    = threadIdx.x;
    const int lane = t & 63;
    const int wid  = t >> 6;
    const int wm   = wid >> 1;          // M half: 32 channels
    const int wn   = wid & 1;           // N half: 64 pixels
    const int n0   = blockIdx.x * 128;
    const int c0   = blockIdx.y * 64;
    const int b    = blockIdx.z;

    const float* W; int cr;
    if (PROJ)           { W = w0; cr = c0; }
    else if (c0 < 512)  { W = w0; cr = c0; }
    else if (c0 < 1024) { W = w1; cr = c0 - 512; }
    else                { W = w2; cr = c0 - 1024; }

    // staging roles (256 threads)
    const int ca  = t >> 2;             // A: channel row 0..63
    const int kga = t & 3;              // A: k-group (8 elems)
    const int nb  = (t & 63) * 2;       // B: pixel pair 0..126
    const int kgb = t >> 6;             // B: k-group

    const float* aptr = W + (size_t)(cr + ca) * KD + kga * 8;
    const float* bpf  = (const float*)Xv + ((size_t)b * KD + kgb * 8) * NPIX + n0 + nb;
    const short* bph  = (const short*)Xv + ((size_t)b * KD + kgb * 8) * NPIX + n0 + nb;

    float areg[8];
    float br0[8], br1[8];
    unsigned bu[8];

    auto gload = [&]() {
        f32x4 a0 = *(const f32x4*)(aptr);
        f32x4 a1 = *(const f32x4*)(aptr + 4);
#pragma unroll
        for (int j = 0; j < 4; ++j) { areg[j] = a0[j]; areg[4 + j] = a1[j]; }
        if (XF32) {
#pragma unroll
            for (int j = 0; j < 8; ++j) {
                f32x2 v = *(const f32x2*)(bpf + (size_t)j * NPIX);
                br0[j] = v[0]; br1[j] = v[1];
            }
        } else {
#pragma unroll
            for (int j = 0; j < 8; ++j)
                bu[j] = *(const unsigned*)(bph + (size_t)j * NPIX);
        }
        aptr += 32;
        bpf += (size_t)32 * NPIX;
        bph += (size_t)32 * NPIX;
    };

    auto swrite = [&](int buf) {
        bf16x8 av, b0v, b1v;
#pragma unroll
        for (int j = 0; j < 8; ++j) av[j] = f2bf(areg[j]);
        if (XF32) {
#pragma unroll
            for (int j = 0; j < 8; ++j) { b0v[j] = f2bf(br0[j]); b1v[j] = f2bf(br1[j]); }
        } else {
#pragma unroll
            for (int j = 0; j < 8; ++j) {
                b0v[j] = (short)(bu[j] & 0xffff);
                b1v[j] = (short)(bu[j] >> 16);
            }
        }
        *(bf16x8*)&Ald[buf][ca * LDK + kga * 8]       = av;
        *(bf16x8*)&Bld[buf][nb * LDK + kgb * 8]       = b0v;
        *(bf16x8*)&Bld[buf][(nb + 1) * LDK + kgb * 8] = b1v;
    };

    f32x4 acc[2][4];
#pragma unroll
    for (int ms = 0; ms < 2; ++ms)
#pragma unroll
        for (int ns = 0; ns < 4; ++ns)
#pragma unroll
            for (int j = 0; j < 4; ++j) acc[ms][ns][j] = 0.f;

    gload();
    swrite(0);
    __syncthreads();

    const int l15 = lane & 15, l4 = lane >> 4;
    for (int s = 0; s < NT; ++s) {
        const int cur = s & 1;
        const bool pf = (s + 1 < NT);
        if (pf) gload();                       // HBM latency hides under MFMA

        bf16x8 af[2], bfr[4];
#pragma unroll
        for (int ms = 0; ms < 2; ++ms)
            af[ms] = *(const bf16x8*)&Ald[cur][(wm * 32 + ms * 16 + l15) * LDK + l4 * 8];
#pragma unroll
        for (int ns = 0; ns < 4; ++ns)
            bfr[ns] = *(const bf16x8*)&Bld[cur][(wn * 64 + ns * 16 + l15) * LDK + l4 * 8];
#pragma unroll
        for (int ms = 0; ms < 2; ++ms)
#pragma unroll
            for (int ns = 0; ns < 4; ++ns)
                acc[ms][ns] = __builtin_amdgcn_mfma_f32_16x16x32_bf16(
                    af[ms], bfr[ns], acc[ms][ns], 0, 0, 0);

        if (pf) swrite(cur ^ 1);               // other buffer: no barrier needed before
        __syncthreads();
    }

    // Epilogue. D: row=(lane>>4)*4+j (channel), col=lane&15 (pixel). [m89]
    if (!PROJ) {
#pragma unroll
        for (int ms = 0; ms < 2; ++ms) {
            const int crow = c0 + wm * 32 + ms * 16 + l4 * 4;
#pragma unroll
            for (int ns = 0; ns < 4; ++ns) {
                const int ncol = n0 + wn * 64 + ns * 16 + l15;
#pragma unroll
                for (int j = 0; j < 4; ++j) {
                    bf16 h; short sv = f2bf(acc[ms][ns][j]);
                    __builtin_memcpy(&h, &sv, 2);
                    Obf[((size_t)b * CALL + crow + j) * NPIX + ncol] = h;
                }
            }
        }
    } else {
#pragma unroll
        for (int ms = 0; ms < 2; ++ms) {
            const int crow = c0 + wm * 32 + ms * 16 + l4 * 4;
#pragma unroll
            for (int j = 0; j < 4; ++j) {
                const int o = crow + j;
                const float inv = gm[o] / sqrtf(va[o] + BN_EPS);
                const float sh  = bt[o] - mu[o] * inv;
#pragma unroll
                for (int ns = 0; ns < 4; ++ns) {
                    const int ncol = n0 + wn * 64 + ns * 16 + l15;
                    const size_t idx = ((size_t)b * 512 + o) * NPIX + ncol;
                    Of[idx] = acc[ms][ns][j] * inv + sh + resid[idx];
                }
            }
        }
    }
}

// ---------------------------------------------------------------------------
// K2: fused depthwise 5x5 (SAME) + grouped 1x1 (8->8). Reads ch [0,1536),
// writes ch [1536,3072). grid (16,192,4), block 256.
__global__ __launch_bounds__(256) void k_dwpw(const float* __restrict__ dwk,
                                              const float* __restrict__ pwk,
                                              bf16* __restrict__ qkv_all) {
    const int n = blockIdx.x * 256 + threadIdx.x;
    const int g = blockIdx.y;
    const int b = blockIdx.z;
    const int y  = n >> 6;
    const int xx = n & 63;

    float dwv[8];
#pragma unroll
    for (int ci = 0; ci < 8; ++ci) {
        const int c = g * 8 + ci;
        const bf16* ip = qkv_all + ((size_t)b * CALL + c) * NPIX;
        const float* kp = dwk + c * 25;
        float s = 0.f;
#pragma unroll
        for (int i = 0; i < 5; ++i) {
            const int yy = y + i - 2;
            if (yy < 0 || yy >= HW) continue;
#pragma unroll
            for (int j = 0; j < 5; ++j) {
                const int xj = xx + j - 2;
                const float v = (xj >= 0 && xj < HW) ? __bfloat162float(ip[yy * HW + xj]) : 0.f;
                s += kp[i * 5 + j] * v;
            }
        }
        dwv[ci] = s;
    }

#pragma unroll
    for (int o = 0; o < 8; ++o) {
        const int co = g * 8 + o;
        float s = 0.f;
#pragma unroll
        for (int ci = 0; ci < 8; ++ci) s += pwk[co * 8 + ci] * dwv[ci];
        qkv_all[((size_t)b * CALL + 1536 + co) * NPIX + n] = __float2bfloat16(s);
    }
}

// ---------------------------------------------------------------------------
// K3: scores[b,h,d,e] = sum_n vpad[d,n]*relu(key[e,n]); partials per n-slice.
__global__ __launch_bounds__(64) void k_scores(const bf16* __restrict__ qkv_all,
                                               float* __restrict__ part) {
    const int lane = threadIdx.x;
    const int h = blockIdx.y;
    const int b = blockIdx.z;
    const bf16* base = qkv_all + ((size_t)b * CALL + h * 24) * NPIX;

    float acc[72];
#pragma unroll
    for (int i = 0; i < 72; ++i) acc[i] = 0.f;

    for (int it = 0; it < 8; ++it) {
        const int n = blockIdx.x * 512 + it * 64 + lane;
        const bf16* p = base + n;
        float kv[8], vv[8];
#pragma unroll
        for (int e = 0; e < 8; ++e) kv[e] = fmaxf(__bfloat162float(p[(size_t)(8 + e) * NPIX]), 0.f);
#pragma unroll
        for (int d = 0; d < 8; ++d) vv[d] = __bfloat162float(p[(size_t)(16 + d) * NPIX]);
#pragma unroll
        for (int d = 0; d < 9; ++d) {
            const float vd = (d < 8) ? vv[d] : 1.f;
#pragma unroll
            for (int e = 0; e < 8; ++e) acc[d * 8 + e] += vd * kv[e];
        }
    }

    const int bh = b * NHEAD + h;
#pragma unroll
    for (int i = 0; i < 72; ++i) {
        float v = acc[i];
        for (int off = 32; off; off >>= 1) v += __shfl_xor(v, off, 64);
        if (lane == 0) part[((size_t)bh * 72 + i) * 8 + blockIdx.x] = v;
    }
}

__global__ __launch_bounds__(128) void k_scores2(const float* __restrict__ part,
                                                 float* __restrict__ scores) {
    const int bh = blockIdx.x;
    const int i = threadIdx.x;
    if (i < 72) {
        float s = 0.f;
#pragma unroll
        for (int ns = 0; ns < 8; ++ns) s += part[((size_t)bh * 72 + i) * 8 + ns];
        scores[(size_t)bh * 72 + i] = s;
    }
}

// ---------------------------------------------------------------------------
// K4a: att[b, h*8+d, n] = (sum_e scores[d,e]*relu(q[e,n])) / (den + EPS)
__global__ __launch_bounds__(256) void k_att(const bf16* __restrict__ qkv_all,
                                             const float* __restrict__ scores,
                                             bf16* __restrict__ att) {
    const int n = blockIdx.x * 256 + threadIdx.x;
    const int h = blockIdx.y;
    const int b = blockIdx.z;

    const bf16* qb = qkv_all + ((size_t)b * CALL + h * 24) * NPIX + n;
    float q[8];
#pragma unroll
    for (int e = 0; e < 8; ++e) q[e] = fmaxf(__bfloat162float(qb[(size_t)e * NPIX]), 0.f);

    const float* sp = scores + (size_t)(b * NHEAD + h) * 72;
    float num[9];
#pragma unroll
    for (int d = 0; d < 9; ++d) {
        float s = 0.f;
#pragma unroll
        for (int e = 0; e < 8; ++e) s += sp[d * 8 + e] * q[e];
        num[d] = s;
    }
    const float invden = 1.f / (num[8] + EPS_LITE);
    bf16* op = att + ((size_t)b * 1024 + h * 8) * NPIX + n;
#pragma unroll
    for (int d = 0; d < 8; ++d) op[(size_t)d * NPIX] = __float2bfloat16(num[d] * invden);
}

// ---------------------------------------------------------------------------
extern "C" void kernel_launch(void* const* d_in, const int* in_sizes, int n_in,
                              void* d_out, int out_size, void* d_ws, size_t ws_size,
                              hipStream_t stream) {
    const float* x   = (const float*)d_in[0];
    const float* wq  = (const float*)d_in[1];
    const float* wk  = (const float*)d_in[2];
    const float* wv  = (const float*)d_in[3];
    const float* dwk = (const float*)d_in[4];
    const float* pwk = (const float*)d_in[5];
    const float* pj  = (const float*)d_in[6];
    const float* gm  = (const float*)d_in[7];
    const float* bt  = (const float*)d_in[8];
    const float* mu  = (const float*)d_in[9];
    const float* va  = (const float*)d_in[10];
    float* out = (float*)d_out;

    char* ws = (char*)d_ws;
    bf16*  qkv_all = (bf16*)(ws);
    bf16*  att     = (bf16*)(ws + 100663296);
    float* part    = (float*)(ws + 134217728);
    float* scores  = (float*)(ws + 135397376);

    // QKV: M=1536, N=4096/batch, K=512
    k_gemm<true, 512, false><<<dim3(32, 24, BATCH), 256, 0, stream>>>(
        x, wq, wk, wv, qkv_all, nullptr, nullptr, nullptr, nullptr, nullptr, nullptr);
    k_dwpw   <<<dim3(16, 192, BATCH), 256, 0, stream>>>(dwk, pwk, qkv_all);
    k_scores <<<dim3( 8, 128, BATCH),  64, 0, stream>>>(qkv_all, part);
    k_scores2<<<dim3(512), 128, 0, stream>>>(part, scores);
    k_att    <<<dim3(16, 128, BATCH), 256, 0, stream>>>(qkv_all, scores, att);
    // Proj: M=512, N=4096/batch, K=1024, + BN + residual
    k_gemm<false, 1024, true><<<dim3(32, 8, BATCH), 256, 0, stream>>>(
        att, pj, pj, pj, nullptr, gm, bt, mu, va, x, out);
}

// Round 4
// 191.841 us; speedup vs baseline: 6.9367x; 2.0562x over previous
//
#include <hip/hip_runtime.h>
#include <hip/hip_bf16.h>

typedef __hip_bfloat16 bf16;
typedef __attribute__((ext_vector_type(8))) short bf16x8;
typedef __attribute__((ext_vector_type(4))) float f32x4;
typedef __attribute__((ext_vector_type(2))) float f32x2;

#define BATCH 4
#define CIN   512
#define HW    64
#define NPIX  4096
#define CALL  3072
#define NHEAD 128
#define EPS_LITE 1e-15f
#define BN_EPS   1e-5f
#define LDK   40            // GEMM LDS K-stride (elems): 80B rows -> 2-way banks (free)

// Workspace (bytes), total ~129.3 MiB:
//   qkv_all (bf16): 0         .. 100663296
//   att     (bf16): 100663296 .. 134217728
//   part    (f32) : 134217728 .. 135397376
//   scores  (f32) : 135397376 .. 135544832

__device__ __forceinline__ short f2bf(float f) {
    __hip_bfloat16 h = __float2bfloat16(f);
    short s; __builtin_memcpy(&s, &h, 2); return s;
}
__device__ __forceinline__ float bfl(unsigned u) {   // low bf16 -> f32
    unsigned v = u << 16; float f; __builtin_memcpy(&f, &v, 4); return f;
}
__device__ __forceinline__ float bfh(unsigned u) {   // high bf16 -> f32
    unsigned v = u & 0xffff0000u; float f; __builtin_memcpy(&f, &v, 4); return f;
}
__device__ __forceinline__ unsigned packbf(float a, float b) {
    return (unsigned)(unsigned short)f2bf(a) | ((unsigned)(unsigned short)f2bf(b) << 16);
}

// ---------------------------------------------------------------------------
// MFMA GEMM: C[c][n] = sum_k W[c][k] * X[k][n], per batch b. (unchanged R3)
template<bool XF32, int KD, bool PROJ>
__global__ __launch_bounds__(256) void k_gemm(
        const void* __restrict__ Xv,
        const float* __restrict__ w0, const float* __restrict__ w1,
        const float* __restrict__ w2,
        bf16* __restrict__ Obf,
        const float* __restrict__ gm, const float* __restrict__ bt,
        const float* __restrict__ mu, const float* __restrict__ va,
        const float* __restrict__ resid, float* __restrict__ Of)
{
    constexpr int NT = KD / 32;
    __shared__ short Ald[2][64 * LDK];
    __shared__ short Bld[2][128 * LDK];

    const int t    = threadIdx.x;
    const int lane = t & 63;
    const int wid  = t >> 6;
    const int wm   = wid >> 1;
    const int wn   = wid & 1;
    const int n0   = blockIdx.x * 128;
    const int c0   = blockIdx.y * 64;
    const int b    = blockIdx.z;

    const float* W; int cr;
    if (PROJ)           { W = w0; cr = c0; }
    else if (c0 < 512)  { W = w0; cr = c0; }
    else if (c0 < 1024) { W = w1; cr = c0 - 512; }
    else                { W = w2; cr = c0 - 1024; }

    const int ca  = t >> 2;
    const int kga = t & 3;
    const int nb  = (t & 63) * 2;
    const int kgb = t >> 6;

    const float* aptr = W + (size_t)(cr + ca) * KD + kga * 8;
    const float* bpf  = (const float*)Xv + ((size_t)b * KD + kgb * 8) * NPIX + n0 + nb;
    const short* bph  = (const short*)Xv + ((size_t)b * KD + kgb * 8) * NPIX + n0 + nb;

    float areg[8];
    float br0[8], br1[8];
    unsigned bu[8];

    auto gload = [&]() {
        f32x4 a0 = *(const f32x4*)(aptr);
        f32x4 a1 = *(const f32x4*)(aptr + 4);
#pragma unroll
        for (int j = 0; j < 4; ++j) { areg[j] = a0[j]; areg[4 + j] = a1[j]; }
        if (XF32) {
#pragma unroll
            for (int j = 0; j < 8; ++j) {
                f32x2 v = *(const f32x2*)(bpf + (size_t)j * NPIX);
                br0[j] = v[0]; br1[j] = v[1];
            }
        } else {
#pragma unroll
            for (int j = 0; j < 8; ++j)
                bu[j] = *(const unsigned*)(bph + (size_t)j * NPIX);
        }
        aptr += 32;
        bpf += (size_t)32 * NPIX;
        bph += (size_t)32 * NPIX;
    };

    auto swrite = [&](int buf) {
        bf16x8 av, b0v, b1v;
#pragma unroll
        for (int j = 0; j < 8; ++j) av[j] = f2bf(areg[j]);
        if (XF32) {
#pragma unroll
            for (int j = 0; j < 8; ++j) { b0v[j] = f2bf(br0[j]); b1v[j] = f2bf(br1[j]); }
        } else {
#pragma unroll
            for (int j = 0; j < 8; ++j) {
                b0v[j] = (short)(bu[j] & 0xffff);
                b1v[j] = (short)(bu[j] >> 16);
            }
        }
        *(bf16x8*)&Ald[buf][ca * LDK + kga * 8]       = av;
        *(bf16x8*)&Bld[buf][nb * LDK + kgb * 8]       = b0v;
        *(bf16x8*)&Bld[buf][(nb + 1) * LDK + kgb * 8] = b1v;
    };

    f32x4 acc[2][4];
#pragma unroll
    for (int ms = 0; ms < 2; ++ms)
#pragma unroll
        for (int ns = 0; ns < 4; ++ns)
#pragma unroll
            for (int j = 0; j < 4; ++j) acc[ms][ns][j] = 0.f;

    gload();
    swrite(0);
    __syncthreads();

    const int l15 = lane & 15, l4 = lane >> 4;
    for (int s = 0; s < NT; ++s) {
        const int cur = s & 1;
        const bool pf = (s + 1 < NT);
        if (pf) gload();

        bf16x8 af[2], bfr[4];
#pragma unroll
        for (int ms = 0; ms < 2; ++ms)
            af[ms] = *(const bf16x8*)&Ald[cur][(wm * 32 + ms * 16 + l15) * LDK + l4 * 8];
#pragma unroll
        for (int ns = 0; ns < 4; ++ns)
            bfr[ns] = *(const bf16x8*)&Bld[cur][(wn * 64 + ns * 16 + l15) * LDK + l4 * 8];
#pragma unroll
        for (int ms = 0; ms < 2; ++ms)
#pragma unroll
            for (int ns = 0; ns < 4; ++ns)
                acc[ms][ns] = __builtin_amdgcn_mfma_f32_16x16x32_bf16(
                    af[ms], bfr[ns], acc[ms][ns], 0, 0, 0);

        if (pf) swrite(cur ^ 1);
        __syncthreads();
    }

    if (!PROJ) {
#pragma unroll
        for (int ms = 0; ms < 2; ++ms) {
            const int crow = c0 + wm * 32 + ms * 16 + l4 * 4;
#pragma unroll
            for (int ns = 0; ns < 4; ++ns) {
                const int ncol = n0 + wn * 64 + ns * 16 + l15;
#pragma unroll
                for (int j = 0; j < 4; ++j) {
                    bf16 h; short sv = f2bf(acc[ms][ns][j]);
                    __builtin_memcpy(&h, &sv, 2);
                    Obf[((size_t)b * CALL + crow + j) * NPIX + ncol] = h;
                }
            }
        }
    } else {
#pragma unroll
        for (int ms = 0; ms < 2; ++ms) {
            const int crow = c0 + wm * 32 + ms * 16 + l4 * 4;
#pragma unroll
            for (int j = 0; j < 4; ++j) {
                const int o = crow + j;
                const float inv = gm[o] / sqrtf(va[o] + BN_EPS);
                const float sh  = bt[o] - mu[o] * inv;
#pragma unroll
                for (int ns = 0; ns < 4; ++ns) {
                    const int ncol = n0 + wn * 64 + ns * 16 + l15;
                    const size_t idx = ((size_t)b * 512 + o) * NPIX + ncol;
                    Of[idx] = acc[ms][ns][j] * inv + sh + resid[idx];
                }
            }
        }
    }
}

// ---------------------------------------------------------------------------
// K2 rewrite: LDS-staged depthwise 5x5 + grouped 1x1.
// Block = (16-row stripe, group of 8 ch, batch). grid (4, 192, 4), 256 thr.
// Phase0: stage 8ch x 20rows x 80cols (halo + zero pads) via uint4.
// Phase1: lane=(xb,ch); sliding 5-row reg window; 25-tap FMA; dw -> bf16 LDS.
// Phase2: pixel-parallel pw 8->8 (wave-uniform weights); packed uint stores.
__global__ __launch_bounds__(256) void k_dwpw(const float* __restrict__ dwk,
                                              const float* __restrict__ pwk,
                                              bf16* __restrict__ qkv_all) {
    __shared__ short in_lds[8 * 20 * 80];   // [ch][row][col], px = col-8, 25.6 KB
    __shared__ short dw_lds[8 * 16 * 64];   // [ch][row][px] bf16, 16 KB

    const int t  = threadIdx.x;
    const int g  = blockIdx.y;
    const int b  = blockIdx.z;
    const int y0 = blockIdx.x * 16;

    // ---- phase 0: stage input rows y0-2 .. y0+17, zero-padded ----
    const bf16* src = qkv_all + ((size_t)b * CALL + g * 8) * NPIX;
#pragma unroll
    for (int i = 0; i < 7; ++i) {
        const int v = i * 256 + t;
        if (v < 1600) {                       // 8ch * 20rows * 10segs
            const int ch  = v / 200;
            const int rem = v % 200;
            const int row = rem / 10;
            const int seg = rem % 10;
            const int grow = y0 + row - 2;
            uint4 val = make_uint4(0u, 0u, 0u, 0u);
            if (seg >= 1 && seg <= 8 && grow >= 0 && grow < HW)
                val = *(const uint4*)(src + (size_t)ch * NPIX + grow * HW + (seg - 1) * 8);
            *(uint4*)&in_lds[ch * 1600 + row * 80 + seg * 8] = val;
        }
    }

    // per-lane dw coefficients (issue before barrier; L2-resident)
    const int lane = t & 63;
    const int w    = t >> 6;
    const int xb   = lane & 7;
    const int ch   = lane >> 3;
    const int x0   = xb * 8;

    float kc[25];
    {
        const float* kp = dwk + (size_t)(g * 8 + ch) * 25;
#pragma unroll
        for (int i = 0; i < 25; ++i) kc[i] = kp[i];
    }
    __syncthreads();

    // ---- phase 1: depthwise. wave w -> output rows w*4 .. w*4+3 ----
    float A[5][12];                            // f[i] = px x0-2+i, rows sliding
    const short* cb = &in_lds[ch * 1600 + x0];

    auto loadrow = [&](int L, float* f) {
        const short* rp = cb + L * 80;
        uint2 lo = *(const uint2*)(rp + 4);    // px x0-4..x0-1
        uint4 md = *(const uint4*)(rp + 8);    // px x0  ..x0+7
        uint2 hi = *(const uint2*)(rp + 16);   // px x0+8..x0+11
        f[0]  = bfl(lo.y); f[1]  = bfh(lo.y);
        f[2]  = bfl(md.x); f[3]  = bfh(md.x);
        f[4]  = bfl(md.y); f[5]  = bfh(md.y);
        f[6]  = bfl(md.z); f[7]  = bfh(md.z);
        f[8]  = bfl(md.w); f[9]  = bfh(md.w);
        f[10] = bfl(hi.x); f[11] = bfh(hi.x);
    };

    const int r0 = w * 4;
    loadrow(r0 + 0, A[0]);
    loadrow(r0 + 1, A[1]);
    loadrow(r0 + 2, A[2]);
    loadrow(r0 + 3, A[3]);

#pragma unroll
    for (int ri = 0; ri < 4; ++ri) {
        loadrow(r0 + ri + 4, A[(ri + 4) % 5]);
        float acc[8];
#pragma unroll
        for (int i = 0; i < 8; ++i) acc[i] = 0.f;
#pragma unroll
        for (int dy = 0; dy < 5; ++dy) {
            const float* Ar = A[(ri + dy) % 5];
#pragma unroll
            for (int dx = 0; dx < 5; ++dx) {
                const float kv = kc[dy * 5 + dx];
#pragma unroll
                for (int i = 0; i < 8; ++i)
                    acc[i] += Ar[i + dx] * kv;
            }
        }
        uint4 pk;
        pk.x = packbf(acc[0], acc[1]);
        pk.y = packbf(acc[2], acc[3]);
        pk.z = packbf(acc[4], acc[5]);
        pk.w = packbf(acc[6], acc[7]);
        *(uint4*)&dw_lds[ch * 1024 + (r0 + ri) * 64 + x0] = pk;
    }
    __syncthreads();

    // ---- phase 2: pointwise 8->8; pwk block-uniform -> s_loads ----
    const float* pwb = pwk + (size_t)g * 64;
#pragma unroll
    for (int it = 0; it < 2; ++it) {
        const int p2 = (it * 256 + t) * 2;     // even pixel index in stripe
        float v0[8], v1[8];
#pragma unroll
        for (int ci = 0; ci < 8; ++ci) {
            const unsigned u = *(const unsigned*)&dw_lds[ci * 1024 + p2];
            v0[ci] = bfl(u); v1[ci] = bfh(u);
        }
        bf16* op = qkv_all + ((size_t)b * CALL + 1536 + g * 8) * NPIX + y0 * HW + p2;
#pragma unroll
        for (int o = 0; o < 8; ++o) {
            float s0 = 0.f, s1 = 0.f;
#pragma unroll
            for (int ci = 0; ci < 8; ++ci) {
                const float wv = pwb[o * 8 + ci];
                s0 += wv * v0[ci]; s1 += wv * v1[ci];
            }
            *(unsigned*)(op + (size_t)o * NPIX) = packbf(s0, s1);
        }
    }
}

// ---------------------------------------------------------------------------
// K3: scores partials; paired bf16 loads. grid (8,128,4), block 64.
__global__ __launch_bounds__(64) void k_scores(const bf16* __restrict__ qkv_all,
                                               float* __restrict__ part) {
    const int lane = threadIdx.x;
    const int h = blockIdx.y;
    const int b = blockIdx.z;
    const bf16* base = qkv_all + ((size_t)b * CALL + h * 24) * NPIX;

    float acc[72];
#pragma unroll
    for (int i = 0; i < 72; ++i) acc[i] = 0.f;

    for (int it = 0; it < 4; ++it) {
        const int n = blockIdx.x * 512 + it * 128 + lane * 2;
        const bf16* p = base + n;
        float k0[8], k1[8], v0[8], v1[8];
#pragma unroll
        for (int e = 0; e < 8; ++e) {
            const unsigned u = *(const unsigned*)&p[(size_t)(8 + e) * NPIX];
            k0[e] = fmaxf(bfl(u), 0.f); k1[e] = fmaxf(bfh(u), 0.f);
        }
#pragma unroll
        for (int d = 0; d < 8; ++d) {
            const unsigned u = *(const unsigned*)&p[(size_t)(16 + d) * NPIX];
            v0[d] = bfl(u); v1[d] = bfh(u);
        }
#pragma unroll
        for (int d = 0; d < 9; ++d) {
            const float vd0 = (d < 8) ? v0[d] : 1.f;
            const float vd1 = (d < 8) ? v1[d] : 1.f;
#pragma unroll
            for (int e = 0; e < 8; ++e)
                acc[d * 8 + e] += vd0 * k0[e] + vd1 * k1[e];
        }
    }

    const int bh = b * NHEAD + h;
#pragma unroll
    for (int i = 0; i < 72; ++i) {
        float v = acc[i];
        for (int off = 32; off; off >>= 1) v += __shfl_xor(v, off, 64);
        if (lane == 0) part[((size_t)bh * 72 + i) * 8 + blockIdx.x] = v;
    }
}

__global__ __launch_bounds__(128) void k_scores2(const float* __restrict__ part,
                                                 float* __restrict__ scores) {
    const int bh = blockIdx.x;
    const int i = threadIdx.x;
    if (i < 72) {
        float s = 0.f;
#pragma unroll
        for (int ns = 0; ns < 8; ++ns) s += part[((size_t)bh * 72 + i) * 8 + ns];
        scores[(size_t)bh * 72 + i] = s;
    }
}

// ---------------------------------------------------------------------------
// K4a: att; 2 px per thread, packed loads/stores. grid (8,128,4), block 256.
__global__ __launch_bounds__(256) void k_att(const bf16* __restrict__ qkv_all,
                                             const float* __restrict__ scores,
                                             bf16* __restrict__ att) {
    const int n2 = (blockIdx.x * 256 + threadIdx.x) * 2;
    const int h = blockIdx.y;
    const int b = blockIdx.z;

    const bf16* qb = qkv_all + ((size_t)b * CALL + h * 24) * NPIX + n2;
    float q0[8], q1[8];
#pragma unroll
    for (int e = 0; e < 8; ++e) {
        const unsigned u = *(const unsigned*)&qb[(size_t)e * NPIX];
        q0[e] = fmaxf(bfl(u), 0.f); q1[e] = fmaxf(bfh(u), 0.f);
    }

    const float* sp = scores + (size_t)(b * NHEAD + h) * 72;   // uniform -> s_load
    float n0[9], n1[9];
#pragma unroll
    for (int d = 0; d < 9; ++d) {
        float s0 = 0.f, s1 = 0.f;
#pragma unroll
        for (int e = 0; e < 8; ++e) {
            const float wv = sp[d * 8 + e];
            s0 += wv * q0[e]; s1 += wv * q1[e];
        }
        n0[d] = s0; n1[d] = s1;
    }
    const float i0 = 1.f / (n0[8] + EPS_LITE);
    const float i1 = 1.f / (n1[8] + EPS_LITE);
    bf16* op = att + ((size_t)b * 1024 + h * 8) * NPIX + n2;
#pragma unroll
    for (int d = 0; d < 8; ++d)
        *(unsigned*)(op + (size_t)d * NPIX) = packbf(n0[d] * i0, n1[d] * i1);
}

// ---------------------------------------------------------------------------
extern "C" void kernel_launch(void* const* d_in, const int* in_sizes, int n_in,
                              void* d_out, int out_size, void* d_ws, size_t ws_size,
                              hipStream_t stream) {
    const float* x   = (const float*)d_in[0];
    const float* wq  = (const float*)d_in[1];
    const float* wk  = (const float*)d_in[2];
    const float* wv  = (const float*)d_in[3];
    const float* dwk = (const float*)d_in[4];
    const float* pwk = (const float*)d_in[5];
    const float* pj  = (const float*)d_in[6];
    const float* gm  = (const float*)d_in[7];
    const float* bt  = (const float*)d_in[8];
    const float* mu  = (const float*)d_in[9];
    const float* va  = (const float*)d_in[10];
    float* out = (float*)d_out;

    char* ws = (char*)d_ws;
    bf16*  qkv_all = (bf16*)(ws);
    bf16*  att     = (bf16*)(ws + 100663296);
    float* part    = (float*)(ws + 134217728);
    float* scores  = (float*)(ws + 135397376);

    k_gemm<true, 512, false><<<dim3(32, 24, BATCH), 256, 0, stream>>>(
        x, wq, wk, wv, qkv_all, nullptr, nullptr, nullptr, nullptr, nullptr, nullptr);
    k_dwpw   <<<dim3( 4, 192, BATCH), 256, 0, stream>>>(dwk, pwk, qkv_all);
    k_scores <<<dim3( 8, 128, BATCH),  64, 0, stream>>>(qkv_all, part);
    k_scores2<<<dim3(512), 128, 0, stream>>>(part, scores);
    k_att    <<<dim3( 8, 128, BATCH), 256, 0, stream>>>(qkv_all, scores, att);
    k_gemm<false, 1024, true><<<dim3(32, 8, BATCH), 256, 0, stream>>>(
        att, pj, pj, pj, nullptr, gm, bt, mu, va, x, out);
}